// Round 2
// baseline (689.282 us; speedup 1.0000x reference)
//
#include <hip/hip_runtime.h>
#include <hip/hip_bf16.h>
#include <math.h>

#define BATCH 8192
#define IN_DIM 1024
#define H_DIM 2048
#define NHEAD 4
#define HEAD_DIM 512
#define EPS_LN 1e-5f

// 256x256 tile, K-step 64, 2-deep LDS double buffer (128 KiB), 8 waves (2Mx4N).
#define BM 256
#define BN 256
#define BK64 64

typedef __bf16 bf16x8 __attribute__((ext_vector_type(8)));
typedef short s16x8 __attribute__((ext_vector_type(8)));
typedef float f32x4 __attribute__((ext_vector_type(4)));

__device__ __forceinline__ float b2f(short s) {
  union { unsigned u; float f; } v;
  v.u = ((unsigned)(unsigned short)s) << 16;
  return v.f;
}
__device__ __forceinline__ short f2b(float f) {
  union { float f; unsigned u; } v;
  v.f = f;
  unsigned r = v.u + 0x7fffu + ((v.u >> 16) & 1u);
  return (short)(r >> 16);
}

__device__ __forceinline__ void async_ld16(const short* g, const short* l) {
  __builtin_amdgcn_global_load_lds(
      (const __attribute__((address_space(1))) void*)g,
      (__attribute__((address_space(3))) void*)l, 16, 0, 0);
}

// fp32 -> bf16 (rne), 8 elements/thread
__global__ __launch_bounds__(256) void cvt_k(const float* __restrict__ s,
                                             short* __restrict__ d, int n) {
  int i = (blockIdx.x * 256 + threadIdx.x) * 8;
  if (i >= n) return;
  f32x4 a = *(const f32x4*)(s + i);
  f32x4 b = *(const f32x4*)(s + i + 4);
  s16x8 o;
#pragma unroll
  for (int j = 0; j < 4; j++) o[j] = f2b(a[j]);
#pragma unroll
  for (int j = 0; j < 4; j++) o[4 + j] = f2b(b[j]);
  *(s16x8*)(d + i) = o;
}

enum { EPI_BIAS = 0, EPI_GELU = 1, EPI_GATE = 2 };

// Stage one K-tile (A 256x64 + B 256x64 bf16) into LDS buffer t&1.
// LDS dest is linear (global_load_lds writes base + lane*16).  Bank-conflict
// swizzle: 16B chunk j of row R stores global chunk j ^ (R&7); applied by
// permuting the GLOBAL source column (inverse == forward, involution).
// Per wave: rows [wv*32, wv*32+32) of A and B; 8 loads/thread/tile.
template <bool DUAL>
__device__ __forceinline__ void stage_tile(
    const short* __restrict__ A, const short* __restrict__ A2,
    const short* __restrict__ W, short* __restrict__ lds, int t, int K,
    int lda, int rowBase, int colBase, int wv, int srow, int schunk) {
  const int k0 = t * BK64;
  const short* Asrc = A;
  int ak = k0;
  if (DUAL && k0 >= H_DIM) { Asrc = A2; ak = k0 - H_DIM; }
  short* As = lds + (t & 1) * (BM * BK64);
  short* Bs = lds + 2 * BM * BK64 + (t & 1) * (BN * BK64);
#pragma unroll
  for (int c = 0; c < 4; c++) {
    const int r = wv * 32 + c * 8;  // 8 rows per wave-instr (64 lanes x 16B)
    async_ld16(Asrc + (size_t)(rowBase + r + srow) * lda + ak + schunk,
               As + r * BK64);
    async_ld16(W + (size_t)(colBase + r + srow) * K + k0 + schunk,
               Bs + r * BK64);
  }
}

// C[M,N] = A[M,K] * W[N,K]^T + bias.  A,W bf16; bias fp32.
// EPI_BIAS/GELU: C bf16.  EPI_GATE: C fp32, fused sigmoid/LN/blend.
// DUAL: k<H_DIM from A, k>=H_DIM from A2.
// Schedule per K-tile t (buf b=t&1):
//   [ds_read kk=0 frags][MFMA x32][ds_read kk=1][lgkmcnt(0)][barrier]
//   [stage tile t+2 -> buf b (now drained by ALL waves)][MFMA x32]
//   [vmcnt(8): tile t+1 landed (only this iter's 8 loads in flight)][barrier]
template <int EPI, bool DUAL>
__global__ __launch_bounds__(512, 2) void gemm_bt(
    const short* __restrict__ A, const short* __restrict__ A2,
    const short* __restrict__ W, const float* __restrict__ bias,
    void* __restrict__ Cv, int K, int lda,
    const short* __restrict__ attg, const float* __restrict__ hprev,
    const float* __restrict__ mu, const float* __restrict__ rstd,
    const float* __restrict__ gamma, const float* __restrict__ beta) {
  extern __shared__ __attribute__((aligned(16))) short lds[];
  const int tid = threadIdx.x;
  const int wv = tid >> 6;
  const int lane = tid & 63;
  const int rowBase = blockIdx.x * BM;   // natural mapping: XCD = bx%8 keeps
  const int colBase = blockIdx.y * BN;   // row-panel affinity (A read once)
  const int wm = wv >> 2;  // 0..1
  const int wn = wv & 3;   // 0..3
  const int fr = lane & 15;
  const int g = lane >> 4;          // k-chunk group 0..3
  const int srow = lane >> 3;       // staging row-in-8
  const int schunk = ((lane & 7) ^ srow) * 8;        // staging src col (elems)
  const int ce0 = ((g ^ (lane & 7)) * 8);            // read col kk=0 (elems)
  const int ce1 = ce0 ^ 32;                          // read col kk=1
  const int apOff = (wm * 128 + fr) * BK64;
  const int bpOff = (wn * 64 + fr) * BK64;
  const int NT = K / BK64;

  f32x4 acc[8][4] = {};

  stage_tile<DUAL>(A, A2, W, lds, 0, K, lda, rowBase, colBase, wv, srow, schunk);
  stage_tile<DUAL>(A, A2, W, lds, 1, K, lda, rowBase, colBase, wv, srow, schunk);
  asm volatile("s_waitcnt vmcnt(8)" ::: "memory");  // tile 0 landed
  __builtin_amdgcn_s_barrier();
  asm volatile("" ::: "memory");

  for (int t = 0; t < NT; ++t) {
    const short* As = lds + (t & 1) * (BM * BK64);
    const short* Bs = lds + 2 * BM * BK64 + (t & 1) * (BN * BK64);
    const short* ap = As + apOff;
    const short* bp = Bs + bpOff;

    bf16x8 a0[8], b0[4];
#pragma unroll
    for (int mi = 0; mi < 8; mi++)
      a0[mi] = *(const bf16x8*)(ap + mi * (16 * BK64) + ce0);
#pragma unroll
    for (int ni = 0; ni < 4; ni++)
      b0[ni] = *(const bf16x8*)(bp + ni * (16 * BK64) + ce0);

    __builtin_amdgcn_s_setprio(1);
#pragma unroll
    for (int mi = 0; mi < 8; mi++)
#pragma unroll
      for (int ni = 0; ni < 4; ni++)
        acc[mi][ni] = __builtin_amdgcn_mfma_f32_16x16x32_bf16(
            a0[mi], b0[ni], acc[mi][ni], 0, 0, 0);
    __builtin_amdgcn_s_setprio(0);

    bf16x8 a1[8], b1[4];
#pragma unroll
    for (int mi = 0; mi < 8; mi++)
      a1[mi] = *(const bf16x8*)(ap + mi * (16 * BK64) + ce1);
#pragma unroll
    for (int ni = 0; ni < 4; ni++)
      b1[ni] = *(const bf16x8*)(bp + ni * (16 * BK64) + ce1);

    // All of this wave's reads of buf b complete; barrier makes it block-wide.
    asm volatile("s_waitcnt lgkmcnt(0)" ::: "memory");
    __builtin_amdgcn_s_barrier();
    asm volatile("" ::: "memory");

    if (t + 2 < NT)
      stage_tile<DUAL>(A, A2, W, lds, t + 2, K, lda, rowBase, colBase, wv,
                       srow, schunk);

    __builtin_amdgcn_s_setprio(1);
#pragma unroll
    for (int mi = 0; mi < 8; mi++)
#pragma unroll
      for (int ni = 0; ni < 4; ni++)
        acc[mi][ni] = __builtin_amdgcn_mfma_f32_16x16x32_bf16(
            a1[mi], b1[ni], acc[mi][ni], 0, 0, 0);
    __builtin_amdgcn_s_setprio(0);

    if (t + 1 < NT) {
      if (t + 2 < NT)
        asm volatile("s_waitcnt vmcnt(8)" ::: "memory");  // tile t+1 landed
      else
        asm volatile("s_waitcnt vmcnt(0)" ::: "memory");  // drain last tile
      __builtin_amdgcn_s_barrier();
      asm volatile("" ::: "memory");
    }
  }

  // C/D layout: col = lane&15, row = (lane>>4)*4 + reg.
  const int ocol0 = colBase + wn * 64 + fr;
  const int orow0 = rowBase + wm * 128 + (g << 2);
#pragma unroll
  for (int mi = 0; mi < 8; mi++) {
#pragma unroll
    for (int ni = 0; ni < 4; ni++) {
      const int col = ocol0 + ni * 16;
      const float bia = bias[col];
#pragma unroll
      for (int r = 0; r < 4; r++) {
        const int row = orow0 + mi * 16 + r;
        float v = acc[mi][ni][r] + bia;
        const size_t idx = (size_t)row * H_DIM + col;
        if (EPI == EPI_BIAS) {
          ((short*)Cv)[idx] = f2b(v);
        } else if (EPI == EPI_GELU) {
          float gg = 0.5f * v * (1.0f + erff(v * 0.70710678118654752f));
          ((short*)Cv)[idx] = f2b(gg);
        } else {
          float gate = 1.0f / (1.0f + expf(-v));
          float hp = hprev[idx];
          float y = hp + b2f(attg[idx]);
          float hc = (y - mu[row]) * rstd[row] * gamma[col] + beta[col];
          ((float*)Cv)[idx] = gate * hc + (1.0f - gate) * hp;
        }
      }
    }
  }
}

// One wave per (b, head). Keys: k1=h, k2=xp, k3=h+xp, k4=h*xp; s3=s1+s2.
// q (bf16) read from `qa`, attn written back over `qa` in place.
__global__ __launch_bounds__(256) void attn_k(short* __restrict__ qa,
                                              const float* __restrict__ h,
                                              const short* __restrict__ xp) {
  const int lane = threadIdx.x & 63;
  const int pair = blockIdx.x * 4 + (threadIdx.x >> 6);  // b*NH + head
  const size_t base =
      (size_t)(pair >> 2) * H_DIM + (size_t)(pair & 3) * HEAD_DIM + lane * 8;
  s16x8 qv = *(const s16x8*)(qa + base);
  f32x4 h0 = *(const f32x4*)(h + base);
  f32x4 h1 = *(const f32x4*)(h + base + 4);
  s16x8 xv = *(const s16x8*)(xp + base);
  float hf[8], xf[8];
  float s1 = 0.f, s2 = 0.f, s4 = 0.f;
#pragma unroll
  for (int j = 0; j < 8; j++) {
    float qf = b2f(qv[j]);
    hf[j] = (j < 4) ? h0[j] : h1[j - 4];
    xf[j] = b2f(xv[j]);
    s1 += qf * hf[j];
    s2 += qf * xf[j];
    s4 += qf * hf[j] * xf[j];
  }
#pragma unroll
  for (int off = 32; off > 0; off >>= 1) {
    s1 += __shfl_xor(s1, off, 64);
    s2 += __shfl_xor(s2, off, 64);
    s4 += __shfl_xor(s4, off, 64);
  }
  const float scale = 0.04419417382415922f;  // 1/sqrt(512)
  float t1 = s1 * scale, t2 = s2 * scale, t3 = (s1 + s2) * scale, t4 = s4 * scale;
  float mx = fmaxf(fmaxf(t1, t2), fmaxf(t3, t4));
  float e1 = expf(t1 - mx), e2 = expf(t2 - mx), e3 = expf(t3 - mx), e4 = expf(t4 - mx);
  float inv = 1.0f / (e1 + e2 + e3 + e4);
  float w1 = e1 * inv, w2 = e2 * inv, w3 = e3 * inv, w4 = e4 * inv;
  float ch = w1 + w3, cx = w2 + w3;
  s16x8 o;
#pragma unroll
  for (int j = 0; j < 8; j++)
    o[j] = f2b(ch * hf[j] + cx * xf[j] + w4 * hf[j] * xf[j]);
  *(s16x8*)(qa + base) = o;
}

// Per-row mean / rstd of (attg(bf16) + h(fp32)).
__global__ __launch_bounds__(256) void rowstats_k(
    const short* __restrict__ attg, const float* __restrict__ h,
    float* __restrict__ mu, float* __restrict__ rstd) {
  __shared__ float sm[8];
  const int row = blockIdx.x;
  const int tid = threadIdx.x;
  const size_t base = (size_t)row * H_DIM + tid * 8;
  s16x8 a = *(const s16x8*)(attg + base);
  f32x4 h0 = *(const f32x4*)(h + base);
  f32x4 h1 = *(const f32x4*)(h + base + 4);
  float s = 0.f, ss = 0.f;
#pragma unroll
  for (int j = 0; j < 8; j++) {
    float y = b2f(a[j]) + ((j < 4) ? h0[j] : h1[j - 4]);
    s += y;
    ss += y * y;
  }
#pragma unroll
  for (int off = 32; off > 0; off >>= 1) {
    s += __shfl_xor(s, off, 64);
    ss += __shfl_xor(ss, off, 64);
  }
  if ((tid & 63) == 0) {
    sm[tid >> 6] = s;
    sm[4 + (tid >> 6)] = ss;
  }
  __syncthreads();
  if (tid == 0) {
    float S = sm[0] + sm[1] + sm[2] + sm[3];
    float SS = sm[4] + sm[5] + sm[6] + sm[7];
    float m = S * (1.0f / H_DIM);
    float var = SS * (1.0f / H_DIM) - m * m;
    mu[row] = m;
    rstd[row] = rsqrtf(fmaxf(var, 0.0f) + EPS_LN);
  }
}

extern "C" void kernel_launch(void* const* d_in, const int* in_sizes, int n_in,
                              void* d_out, int out_size, void* d_ws,
                              size_t ws_size, hipStream_t stream) {
  (void)in_sizes; (void)n_in; (void)out_size; (void)ws_size;
  const float* h_prev = (const float*)d_in[0];
  const float* x      = (const float*)d_in[1];
  const float* W_proj = (const float*)d_in[2];
  const float* b_proj = (const float*)d_in[3];
  const float* W_q    = (const float*)d_in[4];
  const float* b_q    = (const float*)d_in[5];
  const float* W_o    = (const float*)d_in[6];
  const float* b_o    = (const float*)d_in[7];
  const float* W_g    = (const float*)d_in[8];
  const float* b_g    = (const float*)d_in[9];
  const float* gamma  = (const float*)d_in[10];
  const float* beta   = (const float*)d_in[11];
  float* out = (float*)d_out;

  const size_t BH = (size_t)BATCH * H_DIM;       // 16,777,216
  const size_t BI = (size_t)BATCH * IN_DIM;      // 8,388,608
  const size_t NWP = (size_t)H_DIM * IN_DIM;     // 2,097,152
  const size_t NWQ = (size_t)H_DIM * H_DIM;      // 4,194,304
  const size_t NWG = (size_t)H_DIM * 2 * H_DIM;  // 8,388,608

  short* h_bf = (short*)d_ws;
  short* x_bf = h_bf + BH;
  short* wp   = x_bf + BI;
  short* wq   = wp + NWP;
  short* wo   = wq + NWQ;
  short* wg   = wo + NWQ;
  short* bufA = wg + NWG;   // xp, later attn_g
  short* bufB = bufA + BH;  // q, later attn (in place)
  float* mu   = (float*)(bufB + BH);
  float* rstd = mu + BATCH;

  dim3 blk(512);
  dim3 grd(BATCH / BM, H_DIM / BN);  // (32, 8)
  const int SMEM = 2 * 2 * BM * BK64 * (int)sizeof(short);  // 131072
  (void)hipFuncSetAttribute((const void*)gemm_bt<EPI_BIAS, false>,
                            hipFuncAttributeMaxDynamicSharedMemorySize, SMEM);
  (void)hipFuncSetAttribute((const void*)gemm_bt<EPI_GELU, false>,
                            hipFuncAttributeMaxDynamicSharedMemorySize, SMEM);
  (void)hipFuncSetAttribute((const void*)gemm_bt<EPI_GATE, true>,
                            hipFuncAttributeMaxDynamicSharedMemorySize, SMEM);

  dim3 cblk(256);
#define CVT(src, dst, n) \
  cvt_k<<<dim3(((n) / 8 + 255) / 256), cblk, 0, stream>>>(src, dst, (int)(n))

  CVT(h_prev, h_bf, BH);
  CVT(x, x_bf, BI);
  CVT(W_proj, wp, NWP);
  CVT(W_q, wq, NWQ);
  CVT(W_o, wo, NWQ);
  CVT(W_g, wg, NWG);
#undef CVT

  // 1. xp = x @ W_proj^T + b_proj
  gemm_bt<EPI_BIAS, false><<<grd, blk, SMEM, stream>>>(
      x_bf, nullptr, wp, b_proj, bufA, IN_DIM, IN_DIM,
      nullptr, nullptr, nullptr, nullptr, nullptr, nullptr);
  // 2. q = h @ W_q^T + b_q
  gemm_bt<EPI_BIAS, false><<<grd, blk, SMEM, stream>>>(
      h_bf, nullptr, wq, b_q, bufB, H_DIM, H_DIM,
      nullptr, nullptr, nullptr, nullptr, nullptr, nullptr);
  // 3. attention -> bufB (in place over q)
  attn_k<<<dim3(BATCH * NHEAD / 4), cblk, 0, stream>>>(bufB, h_prev, bufA);
  // 4. attn_g = gelu(attn @ W_o^T + b_o) -> bufA
  gemm_bt<EPI_GELU, false><<<grd, blk, SMEM, stream>>>(
      bufB, nullptr, wo, b_o, bufA, H_DIM, H_DIM,
      nullptr, nullptr, nullptr, nullptr, nullptr, nullptr);
  // 5. layernorm stats of (attn_g + h_prev)
  rowstats_k<<<dim3(BATCH), cblk, 0, stream>>>(bufA, h_prev, mu, rstd);
  // 6. gate GEMM (K=4096 over [h, attn_g]) + fused sigmoid/LN/blend -> out
  gemm_bt<EPI_GATE, true><<<grd, blk, SMEM, stream>>>(
      h_bf, bufA, wg, b_g, out, 2 * H_DIM, H_DIM,
      bufA, h_prev, mu, rstd, gamma, beta);
}

// Round 3
// 585.427 us; speedup vs baseline: 1.1774x; 1.1774x over previous
//
#include <hip/hip_runtime.h>
#include <hip/hip_bf16.h>
#include <math.h>

#define BATCH 8192
#define IN_DIM 1024
#define H_DIM 2048
#define NHEAD 4
#define HEAD_DIM 512
#define EPS_LN 1e-5f

// 256x256 tile, K-step 32, 4-deep LDS ring (128 KiB), 8 waves (2M x 4N).
#define BM 256
#define BN 256
#define BKQ 32
#define NBUF 4

typedef __bf16 bf16x8 __attribute__((ext_vector_type(8)));
typedef short s16x8 __attribute__((ext_vector_type(8)));
typedef float f32x4 __attribute__((ext_vector_type(4)));

__device__ __forceinline__ float b2f(short s) {
  union { unsigned u; float f; } v;
  v.u = ((unsigned)(unsigned short)s) << 16;
  return v.f;
}
__device__ __forceinline__ short f2b(float f) {
  union { float f; unsigned u; } v;
  v.f = f;
  unsigned r = v.u + 0x7fffu + ((v.u >> 16) & 1u);
  return (short)(r >> 16);
}

__device__ __forceinline__ void async_ld16(const short* g, const short* l) {
  __builtin_amdgcn_global_load_lds(
      (const __attribute__((address_space(1))) void*)g,
      (__attribute__((address_space(3))) void*)l, 16, 0, 0);
}

// fp32 -> bf16 (rne), 8 elements/thread
__global__ __launch_bounds__(256) void cvt_k(const float* __restrict__ s,
                                             short* __restrict__ d, int n) {
  int i = (blockIdx.x * 256 + threadIdx.x) * 8;
  if (i >= n) return;
  f32x4 a = *(const f32x4*)(s + i);
  f32x4 b = *(const f32x4*)(s + i + 4);
  s16x8 o;
#pragma unroll
  for (int j = 0; j < 4; j++) o[j] = f2b(a[j]);
#pragma unroll
  for (int j = 0; j < 4; j++) o[4 + j] = f2b(b[j]);
  *(s16x8*)(d + i) = o;
}

enum { EPI_BIAS = 0, EPI_GELU = 1, EPI_GATE = 2 };

// Stage one K-tile (A 256x32 + B 256x32 bf16) into LDS ring slot t&3.
// LDS dest is linear (global_load_lds: base + lane*16).  Bank-conflict
// swizzle: stored chunk p of row r holds logical chunk p ^ ((r>>1)&3),
// applied by permuting the GLOBAL source column (involution).  Verified
// conflict-free per consecutive-8-lane ds_read_b128 group (banks
// {0,16,4,20,8,24,12,28} -> full 32-bank coverage).
// Per wave: rows [wv*32, wv*32+32) of A and B; 4 loads/thread/tile.
template <bool DUAL>
__device__ __forceinline__ void stage_tile(
    const short* __restrict__ A, const short* __restrict__ A2,
    const short* __restrict__ W, short* __restrict__ lds, int t, int K,
    int lda, int rowBase, int colBase, int wv, int srow, int schunk) {
  const int k0 = t * BKQ;
  const short* Asrc = A;
  int ak = k0;
  if (DUAL && k0 >= H_DIM) { Asrc = A2; ak = k0 - H_DIM; }
  short* As = lds + (t & (NBUF - 1)) * (BM * BKQ);
  short* Bs = lds + NBUF * BM * BKQ + (t & (NBUF - 1)) * (BN * BKQ);
#pragma unroll
  for (int i = 0; i < 2; i++) {
    const int tt = wv * 2 + i;  // 16-row group
    async_ld16(Asrc + (size_t)(rowBase + tt * 16 + srow) * lda + ak + schunk,
               As + tt * 16 * BKQ);
    async_ld16(W + (size_t)(colBase + tt * 16 + srow) * K + k0 + schunk,
               Bs + tt * 16 * BKQ);
  }
}

// C[M,N] = A[M,K] * W[N,K]^T + bias.  A,W bf16; bias fp32.
// EPI_BIAS/GELU: C bf16.  EPI_GATE: C fp32, fused sigmoid/LN/blend.
// DUAL: k<H_DIM from A, k>=H_DIM from A2.
// Pipeline (round-1 verified): 4-deep ring, stage tile t+3 at top of iter t,
// ONE barrier per K-step with counted vmcnt(8) (2 tiles stay in flight across
// the barrier; ~3 iterations of lead time on every load).  lgkmcnt(0) before
// the barrier makes buffer (t+4)&3 == t&3 safe to overwrite next iter.
template <int EPI, bool DUAL>
__global__ __launch_bounds__(512, 2) void gemm_bt(
    const short* __restrict__ A, const short* __restrict__ A2,
    const short* __restrict__ W, const float* __restrict__ bias,
    void* __restrict__ Cv, int K, int lda,
    const short* __restrict__ attg, const float* __restrict__ hprev,
    const float* __restrict__ mu, const float* __restrict__ rstd,
    const float* __restrict__ gamma, const float* __restrict__ beta) {
  extern __shared__ __attribute__((aligned(16))) short lds[];
  const int tid = threadIdx.x;
  const int wv = tid >> 6;
  const int lane = tid & 63;
  const int rowBase = blockIdx.x * BM;  // natural mapping: L3 absorbs W
  const int colBase = blockIdx.y * BN;  // cross-XCD reuse (147MB ~= ideal)
  const int wm = wv >> 2;  // 0..1
  const int wn = wv & 3;   // 0..3
  const int fr = lane & 15;
  const int g = lane >> 4;                       // k-chunk group 0..3
  const int srow = lane >> 2;                    // staging row-in-16
  const int schunk = ((lane & 3) ^ ((lane >> 3) & 3)) * 8;  // staging src col
  const int cread = ((g ^ ((fr >> 1) & 3)) * 8);            // read-side col
  const int apOff = (wm * 128 + fr) * BKQ + cread;
  const int bpOff = (wn * 64 + fr) * BKQ + cread;
  const int NT = K / BKQ;

  f32x4 acc[8][4] = {};

  stage_tile<DUAL>(A, A2, W, lds, 0, K, lda, rowBase, colBase, wv, srow, schunk);
  stage_tile<DUAL>(A, A2, W, lds, 1, K, lda, rowBase, colBase, wv, srow, schunk);
  stage_tile<DUAL>(A, A2, W, lds, 2, K, lda, rowBase, colBase, wv, srow, schunk);
  asm volatile("s_waitcnt vmcnt(8)" ::: "memory");  // tile 0 landed
  __builtin_amdgcn_s_barrier();
  asm volatile("" ::: "memory");

  for (int t = 0; t < NT; ++t) {
    if (t + 3 < NT)
      stage_tile<DUAL>(A, A2, W, lds, t + 3, K, lda, rowBase, colBase, wv,
                       srow, schunk);

    const short* As = lds + (t & (NBUF - 1)) * (BM * BKQ);
    const short* Bs = lds + NBUF * BM * BKQ + (t & (NBUF - 1)) * (BN * BKQ);
    bf16x8 af[8], bfr[4];
    const short* ap = As + apOff;
#pragma unroll
    for (int mi = 0; mi < 8; mi++)
      af[mi] = *(const bf16x8*)(ap + mi * (16 * BKQ));
    const short* bp = Bs + bpOff;
#pragma unroll
    for (int ni = 0; ni < 4; ni++)
      bfr[ni] = *(const bf16x8*)(bp + ni * (16 * BKQ));

    __builtin_amdgcn_s_setprio(1);
#pragma unroll
    for (int mi = 0; mi < 8; mi++)
#pragma unroll
      for (int ni = 0; ni < 4; ni++)
        acc[mi][ni] = __builtin_amdgcn_mfma_f32_16x16x32_bf16(
            af[mi], bfr[ni], acc[mi][ni], 0, 0, 0);
    __builtin_amdgcn_s_setprio(0);

    if (t + 1 < NT) {
      // lgkmcnt(0): this wave's reads of buf t&3 done; barrier makes it
      // block-wide so next iter's stage of (t+4)&3 == t&3 cannot race.
      // vmcnt leaves tiles beyond t+1 in flight (8 = 2 tiles x 4 loads).
      if (t + 3 < NT)
        asm volatile("s_waitcnt vmcnt(8) lgkmcnt(0)" ::: "memory");
      else if (t + 2 < NT)
        asm volatile("s_waitcnt vmcnt(4) lgkmcnt(0)" ::: "memory");
      else
        asm volatile("s_waitcnt vmcnt(0) lgkmcnt(0)" ::: "memory");
      __builtin_amdgcn_s_barrier();
      asm volatile("" ::: "memory");
    }
  }

  // C/D layout: col = lane&15, row = (lane>>4)*4 + reg.
  const int ocol0 = colBase + wn * 64 + fr;
  const int orow0 = rowBase + wm * 128 + (g << 2);
#pragma unroll
  for (int mi = 0; mi < 8; mi++) {
#pragma unroll
    for (int ni = 0; ni < 4; ni++) {
      const int col = ocol0 + ni * 16;
      const float bia = bias[col];
#pragma unroll
      for (int r = 0; r < 4; r++) {
        const int row = orow0 + mi * 16 + r;
        float v = acc[mi][ni][r] + bia;
        const size_t idx = (size_t)row * H_DIM + col;
        if (EPI == EPI_BIAS) {
          ((short*)Cv)[idx] = f2b(v);
        } else if (EPI == EPI_GELU) {
          float gg = 0.5f * v * (1.0f + erff(v * 0.70710678118654752f));
          ((short*)Cv)[idx] = f2b(gg);
        } else {
          float gate = 1.0f / (1.0f + expf(-v));
          float hp = hprev[idx];
          float y = hp + b2f(attg[idx]);
          float hc = (y - mu[row]) * rstd[row] * gamma[col] + beta[col];
          ((float*)Cv)[idx] = gate * hc + (1.0f - gate) * hp;
        }
      }
    }
  }
}

// One wave per (b, head). Keys: k1=h, k2=xp, k3=h+xp, k4=h*xp; s3=s1+s2.
// q (bf16) read from `qa`, attn written back over `qa` in place.
__global__ __launch_bounds__(256) void attn_k(short* __restrict__ qa,
                                              const float* __restrict__ h,
                                              const short* __restrict__ xp) {
  const int lane = threadIdx.x & 63;
  const int pair = blockIdx.x * 4 + (threadIdx.x >> 6);  // b*NH + head
  const size_t base =
      (size_t)(pair >> 2) * H_DIM + (size_t)(pair & 3) * HEAD_DIM + lane * 8;
  s16x8 qv = *(const s16x8*)(qa + base);
  f32x4 h0 = *(const f32x4*)(h + base);
  f32x4 h1 = *(const f32x4*)(h + base + 4);
  s16x8 xv = *(const s16x8*)(xp + base);
  float hf[8], xf[8];
  float s1 = 0.f, s2 = 0.f, s4 = 0.f;
#pragma unroll
  for (int j = 0; j < 8; j++) {
    float qf = b2f(qv[j]);
    hf[j] = (j < 4) ? h0[j] : h1[j - 4];
    xf[j] = b2f(xv[j]);
    s1 += qf * hf[j];
    s2 += qf * xf[j];
    s4 += qf * hf[j] * xf[j];
  }
#pragma unroll
  for (int off = 32; off > 0; off >>= 1) {
    s1 += __shfl_xor(s1, off, 64);
    s2 += __shfl_xor(s2, off, 64);
    s4 += __shfl_xor(s4, off, 64);
  }
  const float scale = 0.04419417382415922f;  // 1/sqrt(512)
  float t1 = s1 * scale, t2 = s2 * scale, t3 = (s1 + s2) * scale, t4 = s4 * scale;
  float mx = fmaxf(fmaxf(t1, t2), fmaxf(t3, t4));
  float e1 = expf(t1 - mx), e2 = expf(t2 - mx), e3 = expf(t3 - mx), e4 = expf(t4 - mx);
  float inv = 1.0f / (e1 + e2 + e3 + e4);
  float w1 = e1 * inv, w2 = e2 * inv, w3 = e3 * inv, w4 = e4 * inv;
  float ch = w1 + w3, cx = w2 + w3;
  s16x8 o;
#pragma unroll
  for (int j = 0; j < 8; j++)
    o[j] = f2b(ch * hf[j] + cx * xf[j] + w4 * hf[j] * xf[j]);
  *(s16x8*)(qa + base) = o;
}

// Per-row mean / rstd of (attg(bf16) + h(fp32)).
__global__ __launch_bounds__(256) void rowstats_k(
    const short* __restrict__ attg, const float* __restrict__ h,
    float* __restrict__ mu, float* __restrict__ rstd) {
  __shared__ float sm[8];
  const int row = blockIdx.x;
  const int tid = threadIdx.x;
  const size_t base = (size_t)row * H_DIM + tid * 8;
  s16x8 a = *(const s16x8*)(attg + base);
  f32x4 h0 = *(const f32x4*)(h + base);
  f32x4 h1 = *(const f32x4*)(h + base + 4);
  float s = 0.f, ss = 0.f;
#pragma unroll
  for (int j = 0; j < 8; j++) {
    float y = b2f(a[j]) + ((j < 4) ? h0[j] : h1[j - 4]);
    s += y;
    ss += y * y;
  }
#pragma unroll
  for (int off = 32; off > 0; off >>= 1) {
    s += __shfl_xor(s, off, 64);
    ss += __shfl_xor(ss, off, 64);
  }
  if ((tid & 63) == 0) {
    sm[tid >> 6] = s;
    sm[4 + (tid >> 6)] = ss;
  }
  __syncthreads();
  if (tid == 0) {
    float S = sm[0] + sm[1] + sm[2] + sm[3];
    float SS = sm[4] + sm[5] + sm[6] + sm[7];
    float m = S * (1.0f / H_DIM);
    float var = SS * (1.0f / H_DIM) - m * m;
    mu[row] = m;
    rstd[row] = rsqrtf(fmaxf(var, 0.0f) + EPS_LN);
  }
}

extern "C" void kernel_launch(void* const* d_in, const int* in_sizes, int n_in,
                              void* d_out, int out_size, void* d_ws,
                              size_t ws_size, hipStream_t stream) {
  (void)in_sizes; (void)n_in; (void)out_size; (void)ws_size;
  const float* h_prev = (const float*)d_in[0];
  const float* x      = (const float*)d_in[1];
  const float* W_proj = (const float*)d_in[2];
  const float* b_proj = (const float*)d_in[3];
  const float* W_q    = (const float*)d_in[4];
  const float* b_q    = (const float*)d_in[5];
  const float* W_o    = (const float*)d_in[6];
  const float* b_o    = (const float*)d_in[7];
  const float* W_g    = (const float*)d_in[8];
  const float* b_g    = (const float*)d_in[9];
  const float* gamma  = (const float*)d_in[10];
  const float* beta   = (const float*)d_in[11];
  float* out = (float*)d_out;

  const size_t BH = (size_t)BATCH * H_DIM;       // 16,777,216
  const size_t BI = (size_t)BATCH * IN_DIM;      // 8,388,608
  const size_t NWP = (size_t)H_DIM * IN_DIM;     // 2,097,152
  const size_t NWQ = (size_t)H_DIM * H_DIM;      // 4,194,304
  const size_t NWG = (size_t)H_DIM * 2 * H_DIM;  // 8,388,608

  short* h_bf = (short*)d_ws;
  short* x_bf = h_bf + BH;
  short* wp   = x_bf + BI;
  short* wq   = wp + NWP;
  short* wo   = wq + NWQ;
  short* wg   = wo + NWQ;
  short* bufA = wg + NWG;   // xp, later attn_g
  short* bufB = bufA + BH;  // q, later attn (in place)
  float* mu   = (float*)(bufB + BH);
  float* rstd = mu + BATCH;

  dim3 blk(512);
  dim3 grd(BATCH / BM, H_DIM / BN);  // (32, 8)
  const int SMEM = 2 * NBUF * BM * BKQ * (int)sizeof(short);  // 131072
  (void)hipFuncSetAttribute((const void*)gemm_bt<EPI_BIAS, false>,
                            hipFuncAttributeMaxDynamicSharedMemorySize, SMEM);
  (void)hipFuncSetAttribute((const void*)gemm_bt<EPI_GELU, false>,
                            hipFuncAttributeMaxDynamicSharedMemorySize, SMEM);
  (void)hipFuncSetAttribute((const void*)gemm_bt<EPI_GATE, true>,
                            hipFuncAttributeMaxDynamicSharedMemorySize, SMEM);

  dim3 cblk(256);
#define CVT(src, dst, n) \
  cvt_k<<<dim3(((n) / 8 + 255) / 256), cblk, 0, stream>>>(src, dst, (int)(n))

  CVT(h_prev, h_bf, BH);
  CVT(x, x_bf, BI);
  CVT(W_proj, wp, NWP);
  CVT(W_q, wq, NWQ);
  CVT(W_o, wo, NWQ);
  CVT(W_g, wg, NWG);
#undef CVT

  // 1. xp = x @ W_proj^T + b_proj
  gemm_bt<EPI_BIAS, false><<<grd, blk, SMEM, stream>>>(
      x_bf, nullptr, wp, b_proj, bufA, IN_DIM, IN_DIM,
      nullptr, nullptr, nullptr, nullptr, nullptr, nullptr);
  // 2. q = h @ W_q^T + b_q
  gemm_bt<EPI_BIAS, false><<<grd, blk, SMEM, stream>>>(
      h_bf, nullptr, wq, b_q, bufB, H_DIM, H_DIM,
      nullptr, nullptr, nullptr, nullptr, nullptr, nullptr);
  // 3. attention -> bufB (in place over q)
  attn_k<<<dim3(BATCH * NHEAD / 4), cblk, 0, stream>>>(bufB, h_prev, bufA);
  // 4. attn_g = gelu(attn @ W_o^T + b_o) -> bufA
  gemm_bt<EPI_GELU, false><<<grd, blk, SMEM, stream>>>(
      bufB, nullptr, wo, b_o, bufA, H_DIM, H_DIM,
      nullptr, nullptr, nullptr, nullptr, nullptr, nullptr);
  // 5. layernorm stats of (attn_g + h_prev)
  rowstats_k<<<dim3(BATCH), cblk, 0, stream>>>(bufA, h_prev, mu, rstd);
  // 6. gate GEMM (K=4096 over [h, attn_g]) + fused sigmoid/LN/blend -> out
  gemm_bt<EPI_GATE, true><<<grd, blk, SMEM, stream>>>(
      h_bf, bufA, wg, b_g, out, 2 * H_DIM, H_DIM,
      bufA, h_prev, mu, rstd, gamma, beta);
}

// Round 4
// 578.430 us; speedup vs baseline: 1.1916x; 1.0121x over previous
//
#include <hip/hip_runtime.h>
#include <hip/hip_bf16.h>
#include <math.h>

#define BATCH 8192
#define IN_DIM 1024
#define H_DIM 2048
#define NHEAD 4
#define HEAD_DIM 512
#define EPS_LN 1e-5f

// 256x256 tile, K-step 32, 4-deep LDS ring (128 KiB), 8 waves (2M x 4N).
#define BM 256
#define BN 256
#define BKQ 32
#define NBUF 4

typedef __bf16 bf16x8 __attribute__((ext_vector_type(8)));
typedef short s16x8 __attribute__((ext_vector_type(8)));
typedef float f32x4 __attribute__((ext_vector_type(4)));

__device__ __forceinline__ float b2f(short s) {
  union { unsigned u; float f; } v;
  v.u = ((unsigned)(unsigned short)s) << 16;
  return v.f;
}
__device__ __forceinline__ short f2b(float f) {
  union { float f; unsigned u; } v;
  v.f = f;
  unsigned r = v.u + 0x7fffu + ((v.u >> 16) & 1u);
  return (short)(r >> 16);
}

__device__ __forceinline__ void async_ld16(const short* g, const short* l) {
  __builtin_amdgcn_global_load_lds(
      (const __attribute__((address_space(1))) void*)g,
      (__attribute__((address_space(3))) void*)l, 16, 0, 0);
}

// fp32 -> bf16 (rne), 8 elements/thread
__global__ __launch_bounds__(256) void cvt_k(const float* __restrict__ s,
                                             short* __restrict__ d, int n) {
  int i = (blockIdx.x * 256 + threadIdx.x) * 8;
  if (i >= n) return;
  f32x4 a = *(const f32x4*)(s + i);
  f32x4 b = *(const f32x4*)(s + i + 4);
  s16x8 o;
#pragma unroll
  for (int j = 0; j < 4; j++) o[j] = f2b(a[j]);
#pragma unroll
  for (int j = 0; j < 4; j++) o[4 + j] = f2b(b[j]);
  *(s16x8*)(d + i) = o;
}

enum { EPI_BIAS = 0, EPI_GELU = 1, EPI_GATE = 2 };

// Stage one K-tile (A 256x32 + B 256x32 bf16) into LDS ring slot t&3.
// LDS dest linear (global_load_lds: base + lane*16).  Bank-conflict swizzle:
// stored chunk p of row r holds logical chunk p ^ ((r>>1)&3), applied by
// permuting the GLOBAL source column (involution).  Verified conflict-free
// (round 3: SQ_LDS_BANK_CONFLICT == 0).
template <bool DUAL>
__device__ __forceinline__ void stage_tile(
    const short* __restrict__ A, const short* __restrict__ A2,
    const short* __restrict__ W, short* __restrict__ lds, int t, int K,
    int lda, int rowBase, int colBase, int wv, int srow, int schunk) {
  const int k0 = t * BKQ;
  const short* Asrc = A;
  int ak = k0;
  if (DUAL && k0 >= H_DIM) { Asrc = A2; ak = k0 - H_DIM; }
  short* As = lds + (t & (NBUF - 1)) * (BM * BKQ);
  short* Bs = lds + NBUF * BM * BKQ + (t & (NBUF - 1)) * (BN * BKQ);
#pragma unroll
  for (int i = 0; i < 2; i++) {
    const int tt = wv * 2 + i;  // 16-row group
    async_ld16(Asrc + (size_t)(rowBase + tt * 16 + srow) * lda + ak + schunk,
               As + tt * 16 * BKQ);
    async_ld16(W + (size_t)(colBase + tt * 16 + srow) * K + k0 + schunk,
               Bs + tt * 16 * BKQ);
  }
}

// Per-iter body with cross-iteration register double-buffer:
//   stage tile t+3 (4 vm loads);
//   issue ds_reads of tile t+1's fragments into NXT regs (12 lgkm ops);
//   MFMA over CUR regs (read last iter; implicit lgkmcnt(12) is already
//     satisfied -- they completed under last iter's MFMA window);
//   vmcnt(4) [tile t+2 landed for next iter's prefetch] + barrier.
// No lgkmcnt(0) needed: reads of buf t&3 complete before MFMA t (in-wave
// dep), which precedes this barrier; buf t&3 is re-staged only at iter t+1.
#define KBODY(T, CA, CB, NA, NB)                                              \
  {                                                                           \
    const int t_ = (T);                                                       \
    if (t_ + 3 < NT)                                                          \
      stage_tile<DUAL>(A, A2, W, lds, t_ + 3, K, lda, rowBase, colBase, wv,   \
                       srow, schunk);                                         \
    if (t_ + 1 < NT) {                                                        \
      const short* ap_ =                                                      \
          lds + ((t_ + 1) & (NBUF - 1)) * (BM * BKQ) + apOff;                 \
      const short* bp_ = lds + NBUF * BM * BKQ +                              \
                         ((t_ + 1) & (NBUF - 1)) * (BN * BKQ) + bpOff;        \
      _Pragma("unroll") for (int mi = 0; mi < 8; mi++)                        \
          NA[mi] = *(const bf16x8*)(ap_ + mi * (16 * BKQ));                   \
      _Pragma("unroll") for (int ni = 0; ni < 4; ni++)                        \
          NB[ni] = *(const bf16x8*)(bp_ + ni * (16 * BKQ));                   \
    }                                                                         \
    __builtin_amdgcn_s_setprio(1);                                            \
    _Pragma("unroll") for (int mi = 0; mi < 8; mi++)                          \
        _Pragma("unroll") for (int ni = 0; ni < 4; ni++)                      \
            acc[mi][ni] = __builtin_amdgcn_mfma_f32_16x16x32_bf16(            \
                CA[mi], CB[ni], acc[mi][ni], 0, 0, 0);                        \
    __builtin_amdgcn_s_setprio(0);                                            \
    if (t_ + 1 < NT) {                                                        \
      if (t_ + 3 < NT)                                                        \
        asm volatile("s_waitcnt vmcnt(4)" ::: "memory");                      \
      else                                                                    \
        asm volatile("s_waitcnt vmcnt(0)" ::: "memory");                      \
      __builtin_amdgcn_s_barrier();                                           \
      asm volatile("" ::: "memory");                                          \
    }                                                                         \
  }

// C[M,N] = A[M,K] * W[N,K]^T + bias.  A,W bf16; bias fp32.
// EPI_BIAS/GELU: C bf16.  EPI_GATE: C fp32, fused sigmoid/LN/blend.
// DUAL: k<H_DIM from A, k>=H_DIM from A2.
template <int EPI, bool DUAL>
__global__ __launch_bounds__(512, 2) void gemm_bt(
    const short* __restrict__ A, const short* __restrict__ A2,
    const short* __restrict__ W, const float* __restrict__ bias,
    void* __restrict__ Cv, int K, int lda,
    const short* __restrict__ attg, const float* __restrict__ hprev,
    const float* __restrict__ mu, const float* __restrict__ rstd,
    const float* __restrict__ gamma, const float* __restrict__ beta) {
  extern __shared__ __attribute__((aligned(16))) short lds[];
  const int tid = threadIdx.x;
  const int wv = tid >> 6;
  const int lane = tid & 63;
  const int rowBase = blockIdx.x * BM;  // natural mapping: L3 absorbs W
  const int colBase = blockIdx.y * BN;  // cross-XCD reuse (147MB ~= ideal)
  const int wm = wv >> 2;  // 0..1
  const int wn = wv & 3;   // 0..3
  const int fr = lane & 15;
  const int g = lane >> 4;                       // k-chunk group 0..3
  const int srow = lane >> 2;                    // staging row-in-16
  const int schunk = ((lane & 3) ^ ((lane >> 3) & 3)) * 8;  // staging src col
  const int cread = ((g ^ ((fr >> 1) & 3)) * 8);            // read-side col
  const int apOff = (wm * 128 + fr) * BKQ + cread;
  const int bpOff = (wn * 64 + fr) * BKQ + cread;
  const int NT = K / BKQ;  // always even (32/64/128)

  f32x4 acc[8][4] = {};

  stage_tile<DUAL>(A, A2, W, lds, 0, K, lda, rowBase, colBase, wv, srow, schunk);
  stage_tile<DUAL>(A, A2, W, lds, 1, K, lda, rowBase, colBase, wv, srow, schunk);
  stage_tile<DUAL>(A, A2, W, lds, 2, K, lda, rowBase, colBase, wv, srow, schunk);
  asm volatile("s_waitcnt vmcnt(4)" ::: "memory");  // tiles 0 AND 1 landed
  __builtin_amdgcn_s_barrier();
  asm volatile("" ::: "memory");

  // Prologue: fragments for t=0 into set 0.
  bf16x8 fa0[8], fb0[4], fa1[8], fb1[4];
  {
    const short* ap_ = lds + apOff;
    const short* bp_ = lds + NBUF * BM * BKQ + bpOff;
#pragma unroll
    for (int mi = 0; mi < 8; mi++)
      fa0[mi] = *(const bf16x8*)(ap_ + mi * (16 * BKQ));
#pragma unroll
    for (int ni = 0; ni < 4; ni++)
      fb0[ni] = *(const bf16x8*)(bp_ + ni * (16 * BKQ));
  }

  for (int t = 0; t < NT; t += 2) {
    KBODY(t, fa0, fb0, fa1, fb1);
    KBODY(t + 1, fa1, fb1, fa0, fb0);
  }

  // C/D layout: col = lane&15, row = (lane>>4)*4 + reg.
  const int ocol0 = colBase + wn * 64 + fr;
  const int orow0 = rowBase + wm * 128 + (g << 2);
#pragma unroll
  for (int mi = 0; mi < 8; mi++) {
#pragma unroll
    for (int ni = 0; ni < 4; ni++) {
      const int col = ocol0 + ni * 16;
      const float bia = bias[col];
#pragma unroll
      for (int r = 0; r < 4; r++) {
        const int row = orow0 + mi * 16 + r;
        float v = acc[mi][ni][r] + bia;
        const size_t idx = (size_t)row * H_DIM + col;
        if (EPI == EPI_BIAS) {
          ((short*)Cv)[idx] = f2b(v);
        } else if (EPI == EPI_GELU) {
          float gg = 0.5f * v * (1.0f + erff(v * 0.70710678118654752f));
          ((short*)Cv)[idx] = f2b(gg);
        } else {
          float gate = 1.0f / (1.0f + expf(-v));
          float hp = hprev[idx];
          float y = hp + b2f(attg[idx]);
          float hc = (y - mu[row]) * rstd[row] * gamma[col] + beta[col];
          ((float*)Cv)[idx] = gate * hc + (1.0f - gate) * hp;
        }
      }
    }
  }
}

// One wave per (b, head). Keys: k1=h, k2=xp, k3=h+xp, k4=h*xp; s3=s1+s2.
// q (bf16) read from `qa`, attn written back over `qa` in place.
__global__ __launch_bounds__(256) void attn_k(short* __restrict__ qa,
                                              const float* __restrict__ h,
                                              const short* __restrict__ xp) {
  const int lane = threadIdx.x & 63;
  const int pair = blockIdx.x * 4 + (threadIdx.x >> 6);  // b*NH + head
  const size_t base =
      (size_t)(pair >> 2) * H_DIM + (size_t)(pair & 3) * HEAD_DIM + lane * 8;
  s16x8 qv = *(const s16x8*)(qa + base);
  f32x4 h0 = *(const f32x4*)(h + base);
  f32x4 h1 = *(const f32x4*)(h + base + 4);
  s16x8 xv = *(const s16x8*)(xp + base);
  float hf[8], xf[8];
  float s1 = 0.f, s2 = 0.f, s4 = 0.f;
#pragma unroll
  for (int j = 0; j < 8; j++) {
    float qf = b2f(qv[j]);
    hf[j] = (j < 4) ? h0[j] : h1[j - 4];
    xf[j] = b2f(xv[j]);
    s1 += qf * hf[j];
    s2 += qf * xf[j];
    s4 += qf * hf[j] * xf[j];
  }
#pragma unroll
  for (int off = 32; off > 0; off >>= 1) {
    s1 += __shfl_xor(s1, off, 64);
    s2 += __shfl_xor(s2, off, 64);
    s4 += __shfl_xor(s4, off, 64);
  }
  const float scale = 0.04419417382415922f;  // 1/sqrt(512)
  float t1 = s1 * scale, t2 = s2 * scale, t3 = (s1 + s2) * scale, t4 = s4 * scale;
  float mx = fmaxf(fmaxf(t1, t2), fmaxf(t3, t4));
  float e1 = expf(t1 - mx), e2 = expf(t2 - mx), e3 = expf(t3 - mx), e4 = expf(t4 - mx);
  float inv = 1.0f / (e1 + e2 + e3 + e4);
  float w1 = e1 * inv, w2 = e2 * inv, w3 = e3 * inv, w4 = e4 * inv;
  float ch = w1 + w3, cx = w2 + w3;
  s16x8 o;
#pragma unroll
  for (int j = 0; j < 8; j++)
    o[j] = f2b(ch * hf[j] + cx * xf[j] + w4 * hf[j] * xf[j]);
  *(s16x8*)(qa + base) = o;
}

// Per-row mean / rstd of (attg(bf16) + h(fp32)).
__global__ __launch_bounds__(256) void rowstats_k(
    const short* __restrict__ attg, const float* __restrict__ h,
    float* __restrict__ mu, float* __restrict__ rstd) {
  __shared__ float sm[8];
  const int row = blockIdx.x;
  const int tid = threadIdx.x;
  const size_t base = (size_t)row * H_DIM + tid * 8;
  s16x8 a = *(const s16x8*)(attg + base);
  f32x4 h0 = *(const f32x4*)(h + base);
  f32x4 h1 = *(const f32x4*)(h + base + 4);
  float s = 0.f, ss = 0.f;
#pragma unroll
  for (int j = 0; j < 8; j++) {
    float y = b2f(a[j]) + ((j < 4) ? h0[j] : h1[j - 4]);
    s += y;
    ss += y * y;
  }
#pragma unroll
  for (int off = 32; off > 0; off >>= 1) {
    s += __shfl_xor(s, off, 64);
    ss += __shfl_xor(ss, off, 64);
  }
  if ((tid & 63) == 0) {
    sm[tid >> 6] = s;
    sm[4 + (tid >> 6)] = ss;
  }
  __syncthreads();
  if (tid == 0) {
    float S = sm[0] + sm[1] + sm[2] + sm[3];
    float SS = sm[4] + sm[5] + sm[6] + sm[7];
    float m = S * (1.0f / H_DIM);
    float var = SS * (1.0f / H_DIM) - m * m;
    mu[row] = m;
    rstd[row] = rsqrtf(fmaxf(var, 0.0f) + EPS_LN);
  }
}

extern "C" void kernel_launch(void* const* d_in, const int* in_sizes, int n_in,
                              void* d_out, int out_size, void* d_ws,
                              size_t ws_size, hipStream_t stream) {
  (void)in_sizes; (void)n_in; (void)out_size; (void)ws_size;
  const float* h_prev = (const float*)d_in[0];
  const float* x      = (const float*)d_in[1];
  const float* W_proj = (const float*)d_in[2];
  const float* b_proj = (const float*)d_in[3];
  const float* W_q    = (const float*)d_in[4];
  const float* b_q    = (const float*)d_in[5];
  const float* W_o    = (const float*)d_in[6];
  const float* b_o    = (const float*)d_in[7];
  const float* W_g    = (const float*)d_in[8];
  const float* b_g    = (const float*)d_in[9];
  const float* gamma  = (const float*)d_in[10];
  const float* beta   = (const float*)d_in[11];
  float* out = (float*)d_out;

  const size_t BH = (size_t)BATCH * H_DIM;       // 16,777,216
  const size_t BI = (size_t)BATCH * IN_DIM;      // 8,388,608
  const size_t NWP = (size_t)H_DIM * IN_DIM;     // 2,097,152
  const size_t NWQ = (size_t)H_DIM * H_DIM;      // 4,194,304
  const size_t NWG = (size_t)H_DIM * 2 * H_DIM;  // 8,388,608

  short* h_bf = (short*)d_ws;
  short* x_bf = h_bf + BH;
  short* wp   = x_bf + BI;
  short* wq   = wp + NWP;
  short* wo   = wq + NWQ;
  short* wg   = wo + NWQ;
  short* bufA = wg + NWG;   // xp, later attn_g
  short* bufB = bufA + BH;  // q, later attn (in place)
  float* mu   = (float*)(bufB + BH);
  float* rstd = mu + BATCH;

  dim3 blk(512);
  dim3 grd(BATCH / BM, H_DIM / BN);  // (32, 8)
  const int SMEM = 2 * NBUF * BM * BKQ * (int)sizeof(short);  // 131072
  (void)hipFuncSetAttribute((const void*)gemm_bt<EPI_BIAS, false>,
                            hipFuncAttributeMaxDynamicSharedMemorySize, SMEM);
  (void)hipFuncSetAttribute((const void*)gemm_bt<EPI_GELU, false>,
                            hipFuncAttributeMaxDynamicSharedMemorySize, SMEM);
  (void)hipFuncSetAttribute((const void*)gemm_bt<EPI_GATE, true>,
                            hipFuncAttributeMaxDynamicSharedMemorySize, SMEM);

  dim3 cblk(256);
#define CVT(src, dst, n) \
  cvt_k<<<dim3(((n) / 8 + 255) / 256), cblk, 0, stream>>>(src, dst, (int)(n))

  CVT(h_prev, h_bf, BH);
  CVT(x, x_bf, BI);
  CVT(W_proj, wp, NWP);
  CVT(W_q, wq, NWQ);
  CVT(W_o, wo, NWQ);
  CVT(W_g, wg, NWG);
#undef CVT

  // 1. xp = x @ W_proj^T + b_proj
  gemm_bt<EPI_BIAS, false><<<grd, blk, SMEM, stream>>>(
      x_bf, nullptr, wp, b_proj, bufA, IN_DIM, IN_DIM,
      nullptr, nullptr, nullptr, nullptr, nullptr, nullptr);
  // 2. q = h @ W_q^T + b_q
  gemm_bt<EPI_BIAS, false><<<grd, blk, SMEM, stream>>>(
      h_bf, nullptr, wq, b_q, bufB, H_DIM, H_DIM,
      nullptr, nullptr, nullptr, nullptr, nullptr, nullptr);
  // 3. attention -> bufB (in place over q)
  attn_k<<<dim3(BATCH * NHEAD / 4), cblk, 0, stream>>>(bufB, h_prev, bufA);
  // 4. attn_g = gelu(attn @ W_o^T + b_o) -> bufA
  gemm_bt<EPI_GELU, false><<<grd, blk, SMEM, stream>>>(
      bufB, nullptr, wo, b_o, bufA, H_DIM, H_DIM,
      nullptr, nullptr, nullptr, nullptr, nullptr, nullptr);
  // 5. layernorm stats of (attn_g + h_prev)
  rowstats_k<<<dim3(BATCH), cblk, 0, stream>>>(bufA, h_prev, mu, rstd);
  // 6. gate GEMM (K=4096 over [h, attn_g]) + fused sigmoid/LN/blend -> out
  gemm_bt<EPI_GATE, true><<<grd, blk, SMEM, stream>>>(
      h_bf, bufA, wg, b_g, out, 2 * H_DIM, H_DIM,
      bufA, h_prev, mu, rstd, gamma, beta);
}